// Round 5
// baseline (164.532 us; speedup 1.0000x reference)
//
#include <hip/hip_runtime.h>

#define Bn 16
#define Cn 64
#define Hn 128
#define Wn 128
#define HWn (Hn * Wn)

typedef __attribute__((ext_vector_type(8)))  short  short8;    // 8 bf16
typedef __attribute__((ext_vector_type(16))) float  floatx16;  // 32x32 C/D
typedef __attribute__((ext_vector_type(4)))  float  floatx4;
using int32x4 = int __attribute__((ext_vector_type(4)));

__device__ float
llvm_amdgcn_raw_buffer_load_fp32(int32x4 srsrc, int voffset, int soffset,
                                 int aux) __asm("llvm.amdgcn.raw.buffer.load.f32");
__device__ floatx4
llvm_amdgcn_raw_buffer_load_v4f32(int32x4 srsrc, int voffset, int soffset,
                                  int aux) __asm("llvm.amdgcn.raw.buffer.load.v4f32");

__device__ __forceinline__ int32x4 make_rsrc(const void* p, int bytes) {
    int32x4 r;
    r.x = (int)(unsigned)(uintptr_t)p;
    r.y = (int)((uintptr_t)p >> 32);   // stride=0
    r.z = bytes;                        // num_records
    r.w = 0x00020000;                   // raw dword SRD
    return r;
}

__device__ __forceinline__ unsigned short f2bf(float f) {  // RNE f32->bf16
    unsigned u = __float_as_uint(f);
    u += 0x7fffu + ((u >> 16) & 1u);
    return (unsigned short)(u >> 16);
}
__device__ __forceinline__ float lrelu(float v) { return v >= 0.f ? v : 0.1f * v; }

// ---------------------------------------------------------------------------
// Kernel-gen (unchanged from R9). Outputs:
//   kernP[b][c][12]  fp32, taps 0..8 at [0..8], pad [9..11]
//   WcT  [m][g][lane][8] bf16 — A-frag table pre-transposed for coalesced
//     1KB-contiguous wave reads.
// ---------------------------------------------------------------------------
__global__ __launch_bounds__(192)
void gen_kern7(const float* __restrict__ d,
               const float* __restrict__ Wk1,
               const float* __restrict__ Wk2,
               const float* __restrict__ Wc,
               float* __restrict__ kernP,            // ws: [16][64][12]
               unsigned short* __restrict__ WcT) {   // ws: 4096 bf16 (8 KB)
    const int b = blockIdx.x;   // 16
    const int r = blockIdx.y;   // 3
    const int t = threadIdx.x;  // 192
    __shared__ float hid_s[64];

    if (t < 64) {
        const float4* __restrict__ w4 = (const float4*)(Wk1 + (size_t)t * 64);
        const float*  __restrict__ db = d + b * 64;
        float s0 = 0.f, s1 = 0.f, s2 = 0.f, s3 = 0.f;
        #pragma unroll
        for (int j = 0; j < 16; ++j) {
            const float4 wv = w4[j];
            s0 += db[4 * j + 0] * wv.x;
            s1 += db[4 * j + 1] * wv.y;
            s2 += db[4 * j + 2] * wv.z;
            s3 += db[4 * j + 3] * wv.w;
        }
        hid_s[t] = lrelu((s0 + s1) + (s2 + s3));
    }
    __syncthreads();

    {
        const int o = r * 192 + t;                   // 576 = 3*192
        const float4* __restrict__ w4 = (const float4*)(Wk2 + (size_t)o * 64);
        const float4* __restrict__ h4 = (const float4*)hid_s;
        float s0 = 0.f, s1 = 0.f, s2 = 0.f, s3 = 0.f;
        #pragma unroll
        for (int j = 0; j < 16; ++j) {
            const float4 wv = w4[j];
            const float4 hv = h4[j];
            s0 += hv.x * wv.x;
            s1 += hv.y * wv.y;
            s2 += hv.z * wv.z;
            s3 += hv.w * wv.w;
        }
        const int c = o / 9, tap = o - c * 9;
        kernP[b * 768 + c * 12 + tap] = (s0 + s1) + (s2 + s3);
    }

    if (b == 0 && r == 0) {
        for (int idx = t; idx < 4096; idx += 192) {
            const int j    = idx & 7;
            const int lane = (idx >> 3) & 63;
            const int g    = (idx >> 9) & 3;
            const int m    = idx >> 11;
            const int col  = lane & 31, kh = lane >> 5;
            const int o    = m * 32 + col;
            const int c    = g * 16 + kh * 8 + j;
            WcT[idx] = f2bf(Wc[o * 64 + c]);
        }
    }
}

// ---------------------------------------------------------------------------
// Main fused conv, R10 (resubmitted after infra failure): WAVE-AUTONOMOUS,
// zero barriers.
//   R6-R9 all landed ~40-45us regardless of schedule: the invariant was the
//   block-wide barrier convoy (4 waves lock-step, co-resident blocks convoy,
//   per-block critical path ~4us x poorly-overlapped 8 blocks/CU).
//   Fix: each wave stages ALL 16 channels of ITS OWN 32-px tile:
//     staging lane = (sc = lane&15 channel, oct = lane>>4 octet of 8 px),
//     horizontal halo = 2 self-loaded edge columns (6 scalar loads, OOB
//     sentinel at borders -> returns 0 = zero-pad; no shuffles, no
//     cross-lane deps), dw written to a WAVE-PRIVATE LDS patch and read
//     back by the same wave. Producer == consumer => lgkmcnt ordering only,
//     NO s_barrier anywhere. Waves skew freely; TLP (16 waves/CU) hides
//     memory latency instead of convoying on it.
//   LDS: [4 waves][2 buf][16ch][32px] bf16 = 8 KB. Write ds_write_b128
//   linear; read 8x u16, worst 2-way bank (free per m136). Numerics
//   bit-identical to R7-R9 (same tap-sum formulas, same RNE point).
// ---------------------------------------------------------------------------
struct XK { floatx4 v[3][2]; float xl[3], xh[3]; };  // 3 rows x 8 px + halos
struct KF { floatx4 k0, k1; float k8; };             // taps 0..3, 4..7, 8

__device__ __forceinline__ void issue_x(XK& X, int32x4 rs, int c,
                                        const int* rofsB, int px0b,
                                        int loOfs, int hiOfs) {
    #pragma unroll
    for (int r = 0; r < 3; ++r) {
        const int base = (c << 16) + rofsB[r];
        X.v[r][0] = llvm_amdgcn_raw_buffer_load_v4f32(rs, base + px0b, 0, 0);
        X.v[r][1] = llvm_amdgcn_raw_buffer_load_v4f32(rs, base + px0b + 16, 0, 0);
        X.xl[r]   = llvm_amdgcn_raw_buffer_load_fp32 (rs, base + loOfs, 0, 0);
        X.xh[r]   = llvm_amdgcn_raw_buffer_load_fp32 (rs, base + hiOfs, 0, 0);
    }
}

__device__ __forceinline__ void issue_k(KF& kf, const float* kp, int c) {
    const floatx4* k4 = (const floatx4*)(kp + c * 12);
    kf.k0 = k4[0];
    kf.k1 = k4[1];
    kf.k8 = ((const float*)k4)[8];
}

__device__ __forceinline__ short8 compute_dw(const XK& X, const KF& kf) {
    float t0[8], t1[8], t2[8];                // column sums per dx
    #pragma unroll
    for (int i = 0; i < 8; ++i) {
        const float xr0 = (i < 4) ? X.v[0][0][i] : X.v[0][1][i - 4];
        const float xr1 = (i < 4) ? X.v[1][0][i] : X.v[1][1][i - 4];
        const float xr2 = (i < 4) ? X.v[2][0][i] : X.v[2][1][i - 4];
        t0[i] = kf.k0.x * xr0 + kf.k0.w * xr1 + kf.k1.z * xr2; // taps 0,3,6
        t1[i] = kf.k0.y * xr0 + kf.k1.x * xr1 + kf.k1.w * xr2; // taps 1,4,7
        t2[i] = kf.k0.z * xr0 + kf.k1.y * xr1 + kf.k8   * xr2; // taps 2,5,8
    }
    // self-loaded halo columns (OOB loads returned 0 at image borders)
    const float t0m = kf.k0.x * X.xl[0] + kf.k0.w * X.xl[1] + kf.k1.z * X.xl[2];
    const float t2p = kf.k0.z * X.xh[0] + kf.k1.y * X.xh[1] + kf.k8   * X.xh[2];

    float dw[8];
    dw[0] = t0m + t1[0] + t2[1];
    #pragma unroll
    for (int i = 1; i < 7; ++i) dw[i] = t0[i - 1] + t1[i] + t2[i + 1];
    dw[7] = t0[6] + t1[7] + t2p;

    short8 w8;
    #pragma unroll
    for (int i = 0; i < 8; ++i) w8[i] = (short)f2bf(lrelu(dw[i]));
    return w8;
}

__global__ __launch_bounds__(256, 4)
void da_mfma6(const float* __restrict__ x,
              const float* __restrict__ kernP,
              const unsigned short* __restrict__ WcT,
              const float* __restrict__ bc,
              float* __restrict__ out) {
    const int t    = threadIdx.x;
    const int lane = t & 63;
    const int wv   = t >> 6;            // wave 0..3 -> px tile
    const int col  = lane & 31;         // consumer: px within tile
    const int kh   = lane >> 5;         // consumer: k-half (8 ch)
    const int bx   = blockIdx.x;        // 128
    const int h    = ((bx & 7) << 4) | (bx >> 3);   // XCD-band swizzle
    const int b    = blockIdx.y;        // 16
    const int px   = wv * 32 + col;

    // staging roles (wave-local: 16 ch x 4 octets covers 16ch x 32px)
    const int sc   = lane & 15;         // channel within group
    const int oct  = lane >> 4;         // 8-px octet within wave tile
    const int px0  = wv * 32 + oct * 8;

    __shared__ unsigned short dwS[4][2][16][32];   // 8 KB, wave-private patches

    // vertical row byte-offsets; border -> OOB sentinel (loads return 0)
    int rofsB[3];
    #pragma unroll
    for (int i = 0; i < 3; ++i) {
        const int hh = h + i - 1;
        rofsB[i] = (hh >= 0 && hh < Hn) ? hh * (Wn * 4) : 0x10000000;
    }
    // horizontal halo byte-offsets (px part); OOB sentinel at image edges
    const int loOfs = (px0 - 1 >= 0) ? (px0 - 1) * 4 : 0x10000000;
    const int hiOfs = (px0 + 8 < Wn) ? (px0 + 8) * 4 : 0x10000000;
    const int px0b  = px0 * 4;

    const int32x4 rs = make_rsrc(x + (size_t)b * Cn * HWn, Cn * HWn * 4);
    const float* __restrict__ kp = kernP + b * 768;

    floatx16 acc[2];
    #pragma unroll
    for (int m = 0; m < 2; ++m)
        #pragma unroll
        for (int r = 0; r < 16; ++r)
            acc[m][r] = 0.f;

    // ---- prologue: group-0 x in flight ----
    XK X[2];
    issue_x(X[0], rs, sc, rofsB, px0b, loOfs, hiOfs);

    // ---- barrier-free group loop (fully unrolled; cur/nxt compile-time) ----
    #pragma unroll
    for (int g = 0; g < 4; ++g) {
        const int cur = g & 1, nxt = cur ^ 1;
        if (g < 3)  // depth-1 x prefetch: latency covered by this group's work
            issue_x(X[nxt], rs, (g + 1) * 16 + sc, rofsB, px0b, loOfs, hiOfs);

        // A-frags (L2-hot 1KB broadcast), issued before the compute phase
        const short8 a0 = *(const short8*)(WcT + ((0 * 4 + g) * 64 + lane) * 8);
        const short8 a1 = *(const short8*)(WcT + ((1 * 4 + g) * 64 + lane) * 8);

        KF kf;
        issue_k(kf, kp, g * 16 + sc);   // 48B L1-hot after group 0
        const short8 w8 = compute_dw(X[cur], kf);
        *(short8*)&dwS[wv][cur][sc][oct * 8] = w8;     // wave-private write

        short8 bfr;                      // same wave reads back: lgkmcnt only
        #pragma unroll
        for (int j = 0; j < 8; ++j)
            bfr[j] = (short)dwS[wv][cur][kh * 8 + j][col];

        acc[0] = __builtin_amdgcn_mfma_f32_32x32x16_bf16(a0, bfr, acc[0], 0, 0, 0);
        acc[1] = __builtin_amdgcn_mfma_f32_32x32x16_bf16(a1, bfr, acc[1], 0, 0, 0);
    }

    // ---- STORE: full 128B lines; bias added here (float4 bc loads) ----
    float* __restrict__ ob = out + (size_t)b * Cn * HWn + h * Wn + px;
    #pragma unroll
    for (int m = 0; m < 2; ++m)
        #pragma unroll
        for (int q = 0; q < 4; ++q) {
            const float4 bv = *(const float4*)&bc[m * 32 + q * 8 + 4 * kh];
            #pragma unroll
            for (int j = 0; j < 4; ++j) {
                const int o = m * 32 + q * 8 + 4 * kh + j;
                ob[(size_t)o * HWn] = acc[m][q * 4 + j] + ((const float*)&bv)[j];
            }
        }
}

// ---------------------------------------------------------------------------
extern "C" void kernel_launch(void* const* d_in, const int* in_sizes, int n_in,
                              void* d_out, int out_size, void* d_ws, size_t ws_size,
                              hipStream_t stream) {
    const float* x   = (const float*)d_in[0];
    const float* d   = (const float*)d_in[1];
    const float* Wk1 = (const float*)d_in[2];
    const float* Wk2 = (const float*)d_in[3];
    const float* Wc  = (const float*)d_in[4];
    const float* bc  = (const float*)d_in[5];
    float* out = (float*)d_out;
    float*          kernP = (float*)d_ws;                         // 16*768 fp32
    unsigned short* WcT   = (unsigned short*)((float*)d_ws + Bn * 768); // 4096 bf16

    gen_kern7<<<dim3(Bn, 3), dim3(192), 0, stream>>>(d, Wk1, Wk2, Wc, kernP, WcT);
    da_mfma6<<<dim3(Hn, Bn), dim3(256), 0, stream>>>(x, kernP, WcT, bc, out);
}

// Round 6
// 136.198 us; speedup vs baseline: 1.2080x; 1.2080x over previous
//
#include <hip/hip_runtime.h>

#define Bn 16
#define Cn 64
#define Hn 128
#define Wn 128
#define HWn (Hn * Wn)

typedef __attribute__((ext_vector_type(8)))  short  short8;    // 8 bf16
typedef __attribute__((ext_vector_type(16))) float  floatx16;  // 32x32 C/D
typedef __attribute__((ext_vector_type(4)))  float  floatx4;
using int32x4 = int __attribute__((ext_vector_type(4)));

__device__ floatx4
llvm_amdgcn_raw_buffer_load_v4f32(int32x4 srsrc, int voffset, int soffset,
                                  int aux) __asm("llvm.amdgcn.raw.buffer.load.v4f32");

__device__ __forceinline__ int32x4 make_rsrc(const void* p, int bytes) {
    int32x4 r;
    r.x = (int)(unsigned)(uintptr_t)p;
    r.y = (int)((uintptr_t)p >> 32);   // stride=0
    r.z = bytes;                        // num_records
    r.w = 0x00020000;                   // raw dword SRD
    return r;
}

__device__ __forceinline__ unsigned short f2bf(float f) {  // RNE f32->bf16
    unsigned u = __float_as_uint(f);
    u += 0x7fffu + ((u >> 16) & 1u);
    return (unsigned short)(u >> 16);
}
__device__ __forceinline__ float lrelu(float v) { return v >= 0.f ? v : 0.1f * v; }

// Barrier that does NOT drain vmcnt: LDS-only wait + raw s_barrier.
// Cross-wave data is ONLY the dwS LDS buffer, so lgkmcnt(0) suffices;
// x/k/a prefetch results are wave-private registers and stay in flight.
#define SYNC_LDS() asm volatile("s_waitcnt lgkmcnt(0)\n\ts_barrier" ::: "memory")

// ---------------------------------------------------------------------------
// Kernel-gen (unchanged, R5-proven). Outputs:
//   kernP[b][c][12]  fp32, taps 0..8 at [0..8], pad [9..11]
//   WcT  [m][g][lane][8] bf16 — A-frag table pre-transposed for coalesced
//     1KB-contiguous wave reads.
// ---------------------------------------------------------------------------
__global__ __launch_bounds__(192)
void gen_kern7(const float* __restrict__ d,
               const float* __restrict__ Wk1,
               const float* __restrict__ Wk2,
               const float* __restrict__ Wc,
               float* __restrict__ kernP,            // ws: [16][64][12]
               unsigned short* __restrict__ WcT) {   // ws: 4096 bf16 (8 KB)
    const int b = blockIdx.x;   // 16
    const int r = blockIdx.y;   // 3
    const int t = threadIdx.x;  // 192
    __shared__ float hid_s[64];

    if (t < 64) {
        const float4* __restrict__ w4 = (const float4*)(Wk1 + (size_t)t * 64);
        const float*  __restrict__ db = d + b * 64;
        float s0 = 0.f, s1 = 0.f, s2 = 0.f, s3 = 0.f;
        #pragma unroll
        for (int j = 0; j < 16; ++j) {
            const float4 wv = w4[j];
            s0 += db[4 * j + 0] * wv.x;
            s1 += db[4 * j + 1] * wv.y;
            s2 += db[4 * j + 2] * wv.z;
            s3 += db[4 * j + 3] * wv.w;
        }
        hid_s[t] = lrelu((s0 + s1) + (s2 + s3));
    }
    __syncthreads();

    {
        const int o = r * 192 + t;                   // 576 = 3*192
        const float4* __restrict__ w4 = (const float4*)(Wk2 + (size_t)o * 64);
        const float4* __restrict__ h4 = (const float4*)hid_s;
        float s0 = 0.f, s1 = 0.f, s2 = 0.f, s3 = 0.f;
        #pragma unroll
        for (int j = 0; j < 16; ++j) {
            const float4 wv = w4[j];
            const float4 hv = h4[j];
            s0 += hv.x * wv.x;
            s1 += hv.y * wv.y;
            s2 += hv.z * wv.z;
            s3 += hv.w * wv.w;
        }
        const int c = o / 9, tap = o - c * 9;
        kernP[b * 768 + c * 12 + tap] = (s0 + s1) + (s2 + s3);
    }

    if (b == 0 && r == 0) {
        for (int idx = t; idx < 4096; idx += 192) {
            const int j    = idx & 7;
            const int lane = (idx >> 3) & 63;
            const int g    = (idx >> 9) & 3;
            const int m    = idx >> 11;
            const int col  = lane & 31, kh = lane >> 5;
            const int o    = m * 32 + col;
            const int c    = g * 16 + kh * 8 + j;
            WcT[idx] = f2bf(Wc[o * 64 + c]);
        }
    }
}

// ---------------------------------------------------------------------------
// Main fused conv, R11: R9 data path (best measured, ~40.5us; proven
// coalescing + 0 bank conflicts) with 4 phases fused into 2.
//   * Each phase stages TWO 16-ch groups (one load-latency exposure per
//     phase instead of one per group); phase-1's 12 x-loads + k + A-frags
//     are issued BEFORE phase-0's barrier -> they ride under the MFMA
//     phase. Issue order keeps consumers OLDER than prefetches, so the
//     compiler's counted vmcnt waits never drain the pipe.
//   * Disjoint LDS half-buffers per phase (dwS[ph][sub]): only 2 barriers
//     per block (was 4), and no read-protect barrier needed.
//   * sched_barrier(0) fence after the prefetch cluster pins it against
//     the load-sinking observed in R8/R10 (VGPR stuck at 52-60).
//   * Numerics bit-identical to R7-R9 (same tap sums, same RNE point).
// ---------------------------------------------------------------------------
struct XK { floatx4 x[3][2]; };                     // 3 rows x 8 px
struct KF { floatx4 k0, k1; float k8; };            // taps 0..3, 4..7, 8

__device__ __forceinline__ void issue_x(XK& v, int32x4 rs, int c,
                                        const int* rofsB, int px0) {
    #pragma unroll
    for (int r = 0; r < 3; ++r) {
        const int vo = (c << 16) + rofsB[r] + px0 * 4;
        v.x[r][0] = llvm_amdgcn_raw_buffer_load_v4f32(rs, vo, 0, 0);
        v.x[r][1] = llvm_amdgcn_raw_buffer_load_v4f32(rs, vo + 16, 0, 0);
    }
}

__device__ __forceinline__ void issue_k(KF& kf, const float* kp, int c) {
    const floatx4* k4 = (const floatx4*)(kp + c * 12);
    kf.k0 = k4[0];
    kf.k1 = k4[1];
    kf.k8 = ((const float*)k4)[8];
}

__device__ __forceinline__ short8 compute_dw(const XK& v, const KF& kf,
                                             int lane, int tm) {
    float t0[8], t1[8], t2[8];                // column sums per dx
    #pragma unroll
    for (int i = 0; i < 8; ++i) {
        const float xr0 = (i < 4) ? v.x[0][0][i] : v.x[0][1][i - 4];
        const float xr1 = (i < 4) ? v.x[1][0][i] : v.x[1][1][i - 4];
        const float xr2 = (i < 4) ? v.x[2][0][i] : v.x[2][1][i - 4];
        t0[i] = kf.k0.x * xr0 + kf.k0.w * xr1 + kf.k1.z * xr2; // taps 0,3,6
        t1[i] = kf.k0.y * xr0 + kf.k1.x * xr1 + kf.k1.w * xr2; // taps 1,4,7
        t2[i] = kf.k0.z * xr0 + kf.k1.y * xr1 + kf.k8   * xr2; // taps 2,5,8
    }
    // halo from px-octet neighbors (same wave: tm>0 => lane-1 same wave)
    float t0m = __shfl(t0[7], lane - 1, 64);  // left  neighbor's t0[px0-1]
    float t2p = __shfl(t2[0], lane + 1, 64);  // right neighbor's t2[px0+8]
    if (tm == 0)  t0m = 0.f;                  // px = -1  border
    if (tm == 15) t2p = 0.f;                  // px = 128 border

    float dw[8];
    dw[0] = t0m + t1[0] + t2[1];
    #pragma unroll
    for (int i = 1; i < 7; ++i) dw[i] = t0[i - 1] + t1[i] + t2[i + 1];
    dw[7] = t0[6] + t1[7] + t2p;

    short8 w8;
    #pragma unroll
    for (int i = 0; i < 8; ++i) w8[i] = (short)f2bf(lrelu(dw[i]));
    return w8;
}

__global__ __launch_bounds__(256, 4)
void da_mfma7(const float* __restrict__ x,
              const float* __restrict__ kernP,
              const unsigned short* __restrict__ WcT,
              const float* __restrict__ bc,
              float* __restrict__ out) {
    const int t    = threadIdx.x;
    const int lane = t & 63;
    const int wv   = t >> 6;            // wave 0..3 -> px tile
    const int col  = lane & 31;         // px within tile / A-B n,m index
    const int kh   = lane >> 5;         // k-half (8 ch)
    const int bx   = blockIdx.x;        // 128
    const int h    = ((bx & 7) << 4) | (bx >> 3);   // XCD-band swizzle
    const int b    = blockIdx.y;        // 16
    const int px   = wv * 32 + col;

    // staging mapping (R7-R9 proven coalescing: 4 ch x 512B per wave-instr)
    const int sch = t >> 4;             // 0..15 (channel within group)
    const int tm  = t & 15;
    const int px0 = tm * 8;             // 8-px octet

    // dw buffers: [phase][sub-group][16ch][128px] bf16, XOR-32 px swizzle
    __shared__ unsigned short dwS[2][2][2048];   // 16 KB

    // vertical row byte-offsets; border -> OOB sentinel (loads return 0)
    int rofsB[3];
    #pragma unroll
    for (int i = 0; i < 3; ++i) {
        const int hh = h + i - 1;
        rofsB[i] = (hh >= 0 && hh < Hn) ? hh * (Wn * 4) : 0x10000000;
    }

    const int32x4 rs = make_rsrc(x + (size_t)b * Cn * HWn, Cn * HWn * 4);
    const float* __restrict__ kp = kernP + b * 768;

    floatx16 acc[2];
    #pragma unroll
    for (int m = 0; m < 2; ++m)
        #pragma unroll
        for (int r = 0; r < 16; ++r)
            acc[m][r] = 0.f;

    // ---- prologue: phase-0 (groups 0,1) loads in flight ----
    XK X[2]; KF Kf[2];
    issue_k(Kf[0], kp, sch);
    issue_k(Kf[1], kp, 16 + sch);
    issue_x(X[0], rs, sch, rofsB, px0);
    issue_x(X[1], rs, 16 + sch, rofsB, px0);

    // ---- 2 fused phases, 2 barriers total ----
    #pragma unroll
    for (int ph = 0; ph < 2; ++ph) {
        // A-frags for this phase (WcT is L1/L2-hot): issue early, consume
        // after the barrier — latency hidden under the dw computes below.
        short8 a0s[2], a1s[2];
        #pragma unroll
        for (int s = 0; s < 2; ++s) {
            const int g = ph * 2 + s;
            a0s[s] = *(const short8*)(WcT + ((0 * 4 + g) * 64 + lane) * 8);
            a1s[s] = *(const short8*)(WcT + ((1 * 4 + g) * 64 + lane) * 8);
        }

        // compute & write dw for both groups of this phase (one latency
        // exposure: group-1's data arrived while group-0 computed)
        {
            const short8 w0 = compute_dw(X[0], Kf[0], lane, tm);
            *(short8*)&dwS[ph][0][sch * 128 + (px0 ^ ((sch & 8) << 2))] = w0;
            const short8 w1 = compute_dw(X[1], Kf[1], lane, tm);
            *(short8*)&dwS[ph][1][sch * 128 + (px0 ^ ((sch & 8) << 2))] = w1;
        }

        if (ph == 0) {   // next-phase prefetch: rides under MFMA phase
            issue_x(X[0], rs, 2 * 16 + sch, rofsB, px0);
            issue_x(X[1], rs, 3 * 16 + sch, rofsB, px0);
            issue_k(Kf[0], kp, 2 * 16 + sch);
            issue_k(Kf[1], kp, 3 * 16 + sch);
            __builtin_amdgcn_sched_barrier(0);   // pin: no sinking past here
        }

        SYNC_LDS();      // lgkm-only: dw visible, vmcnt prefetch stays live

        #pragma unroll
        for (int s = 0; s < 2; ++s) {
            short8 bfr;   // 8x ds_read_u16, banks balanced via XOR-32 swizzle
            #pragma unroll
            for (int j = 0; j < 8; ++j) {
                const int cl = kh * 8 + j;
                bfr[j] = (short)dwS[ph][s][cl * 128 + (px ^ ((cl & 8) << 2))];
            }
            acc[0] = __builtin_amdgcn_mfma_f32_32x32x16_bf16(a0s[s], bfr, acc[0], 0, 0, 0);
            acc[1] = __builtin_amdgcn_mfma_f32_32x32x16_bf16(a1s[s], bfr, acc[1], 0, 0, 0);
        }
        // no read-protect barrier: phase 1 writes dwS[1], disjoint from dwS[0]
    }

    // ---- STORE: full 128B lines; bias added here (float4 bc loads) ----
    float* __restrict__ ob = out + (size_t)b * Cn * HWn + h * Wn + px;
    #pragma unroll
    for (int m = 0; m < 2; ++m)
        #pragma unroll
        for (int q = 0; q < 4; ++q) {
            const float4 bv = *(const float4*)&bc[m * 32 + q * 8 + 4 * kh];
            #pragma unroll
            for (int j = 0; j < 4; ++j) {
                const int o = m * 32 + q * 8 + 4 * kh + j;
                ob[(size_t)o * HWn] = acc[m][q * 4 + j] + ((const float*)&bv)[j];
            }
        }
}

// ---------------------------------------------------------------------------
extern "C" void kernel_launch(void* const* d_in, const int* in_sizes, int n_in,
                              void* d_out, int out_size, void* d_ws, size_t ws_size,
                              hipStream_t stream) {
    const float* x   = (const float*)d_in[0];
    const float* d   = (const float*)d_in[1];
    const float* Wk1 = (const float*)d_in[2];
    const float* Wk2 = (const float*)d_in[3];
    const float* Wc  = (const float*)d_in[4];
    const float* bc  = (const float*)d_in[5];
    float* out = (float*)d_out;
    float*          kernP = (float*)d_ws;                         // 16*768 fp32
    unsigned short* WcT   = (unsigned short*)((float*)d_ws + Bn * 768); // 4096 bf16

    gen_kern7<<<dim3(Bn, 3), dim3(192), 0, stream>>>(d, Wk1, Wk2, Wc, kernP, WcT);
    da_mfma7<<<dim3(Hn, Bn), dim3(256), 0, stream>>>(x, kernP, WcT, bc, out);
}